// Round 1
// baseline (252.564 us; speedup 1.0000x reference)
//
#include <hip/hip_runtime.h>

#define DIM        512
#define B_POS      1024
#define N_NEG      8192
#define N_RULES    20
#define NBLK_NEG   2048   // 4 waves/block -> 8192 waves, 1 per negative
#define NBLK_POS   256    // 4 waves/block -> 1024 waves, 1 per positive
#define NPART      (NBLK_NEG + NBLK_POS)   // 2304 partials, reduced by K3

__device__ __forceinline__ float4 f4sub(float4 a, float4 b) {
    return make_float4(a.x - b.x, a.y - b.y, a.z - b.z, a.w - b.w);
}
__device__ __forceinline__ float4 f4add(float4 a, float4 b) {
    return make_float4(a.x + b.x, a.y + b.y, a.z + b.z, a.w + b.w);
}
__device__ __forceinline__ float dot4(float4 a, float4 b) {
    return a.x * b.x + a.y * b.y + a.z * b.z + a.w * b.w;
}

__device__ __forceinline__ float wave_sum(float x) {
#pragma unroll
    for (int off = 32; off > 0; off >>= 1)
        x += __shfl_xor(x, off, 64);
    return x;
}

// TransH distance with d = he - te already in registers.
// ||d + re - ((d.w)/(w.w)) w|| = sqrt( ||d+re||^2 - (d.w)((d.w) + 2(re.w))/(w.w) )
// One row pass -> 4 scalar accumulators -> ONE interleaved 6-step butterfly.
__device__ __forceinline__ float dist_from_d(
    float4 d0, float4 d1, int r,
    const float* __restrict__ rel, const float* __restrict__ nv, int lane)
{
    const float4* wp = (const float4*)(nv  + (size_t)r * DIM);
    const float4* rp = (const float4*)(rel + (size_t)r * DIM);
    float4 w0 = wp[lane], w1 = wp[lane + 64];
    float4 r0 = rp[lane], r1 = rp[lane + 64];
    float4 s0 = f4add(d0, r0), s1 = f4add(d1, r1);
    float a  = dot4(s0, s0) + dot4(s1, s1);   // ||d+re||^2 partial
    float b  = dot4(d0, w0) + dot4(d1, w1);   // d.w partial
    float ww = dot4(w0, w0) + dot4(w1, w1);   // w.w partial
    float rw = dot4(r0, w0) + dot4(r1, w1);   // re.w partial
#pragma unroll
    for (int off = 32; off > 0; off >>= 1) {
        a  += __shfl_xor(a,  off, 64);
        b  += __shfl_xor(b,  off, 64);
        ww += __shfl_xor(ww, off, 64);
        rw += __shfl_xor(rw, off, 64);
    }
    return sqrtf(fmaxf(a - b * (b + 2.f * rw) / ww, 0.f));
}

// K1: one wave per pos triple. Computes d_pos[i] once (was recomputed x8),
// plus ALL rule terms for that triple (reusing in-register d).
__global__ __launch_bounds__(256) void pos_rule_kernel(
    const int* __restrict__ pos,
    const int* __restrict__ rule_r1, const int* __restrict__ rule_r2,
    const float* __restrict__ rule_conf,
    const float* __restrict__ ent, const float* __restrict__ rel,
    const float* __restrict__ nv,
    float* __restrict__ d_pos, float* __restrict__ rulepart)
{
    int w = threadIdx.x >> 6, lane = threadIdx.x & 63;
    int i = blockIdx.x * 4 + w;                 // 0..1023
    int h = pos[3 * i], r = pos[3 * i + 1], t = pos[3 * i + 2];
    const float4* hp = (const float4*)(ent + (size_t)h * DIM);
    const float4* tp = (const float4*)(ent + (size_t)t * DIM);
    float4 d0 = f4sub(hp[lane],      tp[lane]);
    float4 d1 = f4sub(hp[lane + 64], tp[lane + 64]);

    float dp = dist_from_d(d0, d1, r, rel, nv, lane);
    if (lane == 0) d_pos[i] = dp;

    // rule loss: sum over j with r1[j]==r of conf_j * dist(h, r2[j], t).
    // ~41 matches total across all 1024 triples -> keep loop rolled.
    float racc = 0.f;
#pragma unroll 1
    for (int j = 0; j < N_RULES; ++j) {
        if (r == rule_r1[j]) {
            racc += rule_conf[j] * dist_from_d(d0, d1, rule_r2[j], rel, nv, lane);
        }
    }
    __shared__ float part[4];
    if (lane == 0) part[w] = 0.5f * racc;       // RULE_WEIGHT folded in here
    __syncthreads();
    if (threadIdx.x == 0)
        rulepart[blockIdx.x] = part[0] + part[1] + part[2] + part[3];
}

// K2: one wave per negative. Single distance + 4B d_pos lookup.
__global__ __launch_bounds__(256) void neg_kernel(
    const int* __restrict__ neg, const float* __restrict__ d_pos,
    const float* __restrict__ ent, const float* __restrict__ rel,
    const float* __restrict__ nv,
    float* __restrict__ partial)
{
    int w = threadIdx.x >> 6, lane = threadIdx.x & 63;
    int n = blockIdx.x * 4 + w;                 // 0..8191
    int h = neg[3 * n], r = neg[3 * n + 1], t = neg[3 * n + 2];
    const float4* hp = (const float4*)(ent + (size_t)h * DIM);
    const float4* tp = (const float4*)(ent + (size_t)t * DIM);
    float4 d0 = f4sub(hp[lane],      tp[lane]);
    float4 d1 = f4sub(hp[lane + 64], tp[lane + 64]);

    float dn = dist_from_d(d0, d1, r, rel, nv, lane);
    float v = 1.0f + d_pos[n >> 3] - dn;
    float contrib = ((v > 0.f) ? v : 0.f) * (1.0f / (float)N_NEG);

    __shared__ float part[4];
    if (lane == 0) part[w] = contrib;
    __syncthreads();
    if (threadIdx.x == 0)
        partial[blockIdx.x] = part[0] + part[1] + part[2] + part[3];
}

// K3: deterministic reduce of 2048 neg partials + 256 rule partials.
__global__ __launch_bounds__(256) void final_reduce(
    const float* __restrict__ partial, float* __restrict__ out)
{
    int t = threadIdx.x;
    float s = 0.f;
#pragma unroll
    for (int m = 0; m < NPART / 256; ++m)       // 9 strided reads, covers all 2304
        s += partial[t + 256 * m];
    s = wave_sum(s);
    __shared__ float part[4];
    int w = t >> 6, lane = t & 63;
    if (lane == 0) part[w] = s;
    __syncthreads();
    if (t == 0) out[0] = part[0] + part[1] + part[2] + part[3];
}

extern "C" void kernel_launch(void* const* d_in, const int* in_sizes, int n_in,
                              void* d_out, int out_size, void* d_ws, size_t ws_size,
                              hipStream_t stream) {
    const int*   pos       = (const int*)  d_in[0];
    const int*   neg       = (const int*)  d_in[1];
    const int*   rule_r1   = (const int*)  d_in[2];
    const int*   rule_r2   = (const int*)  d_in[3];
    const float* rule_conf = (const float*)d_in[4];
    const float* ent       = (const float*)d_in[5];
    const float* rel       = (const float*)d_in[6];
    const float* nv        = (const float*)d_in[7];
    float* out = (float*)d_out;

    // ws layout (floats): [0,2048) neg partials | [2048,2304) rule partials |
    //                     [2304,3328) d_pos.  All slots written every launch.
    float* partial  = (float*)d_ws;
    float* rulepart = partial + NBLK_NEG;
    float* d_pos    = partial + NPART;

    pos_rule_kernel<<<NBLK_POS, 256, 0, stream>>>(pos, rule_r1, rule_r2, rule_conf,
                                                  ent, rel, nv, d_pos, rulepart);
    neg_kernel<<<NBLK_NEG, 256, 0, stream>>>(neg, d_pos, ent, rel, nv, partial);
    final_reduce<<<1, 256, 0, stream>>>(partial, out);
}